// Round 1
// baseline (674.580 us; speedup 1.0000x reference)
//
#include <hip/hip_runtime.h>
#include <math.h>

// Problem constants (B,L,D,H,K) = (8, 2048, 1024, 16, 31)
#define BB 8
#define LL 2048
#define DD 1024
#define HH 16
#define DH 64          // D/H
#define KK 31
#define NSEG 32
#define SEGLEN 64      // LL/NSEG

#define TLEN 64        // tokens per conv block
#define WIN 94         // TLEN + KK - 1
#define WSTR 68        // win row stride (floats), keeps float4 alignment
#define PSTR 65        // pc row stride (floats), breaks bank collisions

// ---------------- Pass 1a: per-segment sums (for parallel cumsum) ----------
__global__ __launch_bounds__(256)
void seg_sum_kernel(const float* __restrict__ x, float* __restrict__ segsum) {
    int g = blockIdx.x * 256 + threadIdx.x;   // B*NSEG*D threads
    int d = g & (DD - 1);
    int s = (g >> 10) & (NSEG - 1);
    int b = g >> 15;
    const float* p = x + (size_t)(b * LL + s * SEGLEN) * DD + d;
    float acc = 0.f;
    #pragma unroll 8
    for (int i = 0; i < SEGLEN; ++i) acc += p[(size_t)i * DD];
    segsum[g] = acc;   // layout [b][s][d] == flat g
}

// ---------------- Pass 1b: running mean avg[b,t,d] = cumsum/(t+1) ----------
__global__ __launch_bounds__(256)
void avg_kernel(const float* __restrict__ x, const float* __restrict__ segsum,
                float* __restrict__ avg) {
    int g = blockIdx.x * 256 + threadIdx.x;
    int d = g & (DD - 1);
    int s = (g >> 10) & (NSEG - 1);
    int b = g >> 15;
    float run = 0.f;
    const float* ss = segsum + ((size_t)b << 15) + d;
    for (int s2 = 0; s2 < s; ++s2) run += ss[s2 << 10];
    const float* p = x + (size_t)(b * LL + s * SEGLEN) * DD + d;
    float* q = avg + (size_t)(b * LL + s * SEGLEN) * DD + d;
    int t0 = s * SEGLEN;
    #pragma unroll 4
    for (int i = 0; i < SEGLEN; ++i) {
        run += p[(size_t)i * DD];
        q[(size_t)i * DD] = run / (float)(t0 + i + 1);
    }
}

// ------- Fused: pc = ci@W_pe+b_pe -> gated energy -> softmax -> local conv --
__global__ __launch_bounds__(256)
void conv_kernel(const float* __restrict__ avg, const float* __restrict__ W_pe,
                 const float* __restrict__ b_pe, const float* __restrict__ stt,
                 float* __restrict__ conv) {
    __shared__ float win[WIN * WSTR];   // ci window rows t0-30 .. t0+63  (25.6KB)
    __shared__ float wpe[64 * 64];      // W_pe padded to 64 cols         (16.4KB)
    __shared__ float pcs[TLEN * PSTR];  // pc rows -> then weights        (16.6KB)

    int tid = threadIdx.x;
    int tile = blockIdx.x & 31;
    int bh = blockIdx.x >> 5;
    int b = bh >> 4, h = bh & 15;
    int t0 = tile * TLEN;

    // stage W_pe (zero-pad cols 62,63)
    for (int i = tid; i < 64 * 64; i += 256) {
        int j = i >> 6, k = i & 63;
        wpe[i] = (k < 2 * KK) ? W_pe[j * (2 * KK) + k] : 0.f;
    }
    // stage ci window
    const float* base = avg + (size_t)(b * LL) * DD + h * DH;
    for (int i = tid; i < WIN * DH; i += 256) {
        int r = i >> 6, j = i & 63;
        int g = t0 - (KK - 1) + r;
        win[r * WSTR + j] = (g >= 0) ? base[(size_t)g * DD + j] : 0.f;
    }
    __syncthreads();

    // pc[tok][col] = b_pe[col] + sum_j ci[tok][j] * W_pe[j][col]   (4x4 micro)
    {
        int tx = tid & 15, ty = tid >> 4;
        int c0 = tx * 4, t4 = ty * 4;
        float acc[4][4];
        #pragma unroll
        for (int i = 0; i < 4; ++i)
            #pragma unroll
            for (int c = 0; c < 4; ++c)
                acc[i][c] = (c0 + c < 2 * KK) ? b_pe[c0 + c] : 0.f;
        for (int j = 0; j < 64; ++j) {
            float4 bv = *(const float4*)&wpe[j * 64 + c0];
            #pragma unroll
            for (int i = 0; i < 4; ++i) {
                float a = win[(t4 + i + (KK - 1)) * WSTR + j];
                acc[i][0] += a * bv.x; acc[i][1] += a * bv.y;
                acc[i][2] += a * bv.z; acc[i][3] += a * bv.w;
            }
        }
        #pragma unroll
        for (int i = 0; i < 4; ++i)
            #pragma unroll
            for (int c = 0; c < 4; ++c)
                pcs[(t4 + i) * PSTR + c0 + c] = acc[i][c];
    }
    __syncthreads();

    // softmax weights: energy = stt + sigmoid(gate)*dyn ; mask AFTER softmax
    {
        int lane = tid & 63, w = tid >> 6;
        float sttk = (lane < KK) ? stt[h * KK + lane] : 0.f;
        for (int it = 0; it < 16; ++it) {
            int tok = w * 16 + it;
            float dyn  = pcs[tok * PSTR + lane];
            int gi = tok * PSTR + KK + ((lane < KK) ? lane : 0);
            float gate = pcs[gi];
            float en = (lane < KK) ? sttk + dyn / (1.f + __expf(-gate)) : -3.0e38f;
            float m = en;
            #pragma unroll
            for (int off = 32; off; off >>= 1) m = fmaxf(m, __shfl_xor(m, off, 64));
            float e = (lane < KK) ? __expf(en - m) : 0.f;
            float sum = e;
            #pragma unroll
            for (int off = 32; off; off >>= 1) sum += __shfl_xor(sum, off, 64);
            float wv = e / sum;
            if (t0 + tok + lane < KK - 1) wv = 0.f;   // causal mask (post-softmax)
            if (lane < KK) pcs[tok * PSTR + lane] = wv;
        }
    }
    __syncthreads();

    // conv: out[tok][j] = sum_k w[tok][k] * ci[tok+k-30][j]
    {
        int tok = tid >> 2;
        int jg = (tid & 3) * 16;
        float wreg[KK];
        #pragma unroll
        for (int k = 0; k < KK; ++k) wreg[k] = pcs[tok * PSTR + k];
        float acc[16];
        #pragma unroll
        for (int q = 0; q < 16; ++q) acc[q] = 0.f;
        for (int k = 0; k < KK; ++k) {
            const float* wr = &win[(tok + k) * WSTR + jg];
            float wk = wreg[k];
            #pragma unroll
            for (int q4 = 0; q4 < 4; ++q4) {
                float4 a = *(const float4*)&wr[q4 * 4];
                acc[q4 * 4 + 0] += wk * a.x; acc[q4 * 4 + 1] += wk * a.y;
                acc[q4 * 4 + 2] += wk * a.z; acc[q4 * 4 + 3] += wk * a.w;
            }
        }
        float* o = conv + (size_t)(b * LL + t0 + tok) * DD + h * DH + jg;
        #pragma unroll
        for (int q4 = 0; q4 < 4; ++q4)
            *(float4*)&o[q4 * 4] = make_float4(acc[q4 * 4], acc[q4 * 4 + 1],
                                               acc[q4 * 4 + 2], acc[q4 * 4 + 3]);
    }
}

// ------------- v = conv @ W_fc^T + x  (f32, 128x128x16 tile) ---------------
__global__ __launch_bounds__(256)
void gemm_kernel(const float* __restrict__ A,   // conv (16384 x 1024)
                 const float* __restrict__ W,   // W_fc (1024 x 1024), used as [n][k]
                 const float* __restrict__ X,   // residual
                 float* __restrict__ V)         // v -> d_out
{
    __shared__ float As[16][128];
    __shared__ float Bs[16][128];
    int tid = threadIdx.x;
    int bn0 = blockIdx.x * 128;
    int bm0 = blockIdx.y * 128;
    int tx = tid & 15, ty = tid >> 4;
    float acc[8][8] = {};
    for (int kt = 0; kt < 1024; kt += 16) {
        #pragma unroll
        for (int q = 0; q < 2; ++q) {
            int id = tid + q * 256;
            int r = id >> 2;
            int c4 = (id & 3) << 2;
            float4 av = *(const float4*)&A[(size_t)(bm0 + r) * 1024 + kt + c4];
            As[c4 + 0][r] = av.x; As[c4 + 1][r] = av.y;
            As[c4 + 2][r] = av.z; As[c4 + 3][r] = av.w;
            float4 bv = *(const float4*)&W[(size_t)(bn0 + r) * 1024 + kt + c4];
            Bs[c4 + 0][r] = bv.x; Bs[c4 + 1][r] = bv.y;
            Bs[c4 + 2][r] = bv.z; Bs[c4 + 3][r] = bv.w;
        }
        __syncthreads();
        #pragma unroll
        for (int kk = 0; kk < 16; ++kk) {
            float a[8], bq[8];
            *(float4*)&a[0]  = *(const float4*)&As[kk][ty * 8];
            *(float4*)&a[4]  = *(const float4*)&As[kk][ty * 8 + 4];
            *(float4*)&bq[0] = *(const float4*)&Bs[kk][tx * 8];
            *(float4*)&bq[4] = *(const float4*)&Bs[kk][tx * 8 + 4];
            #pragma unroll
            for (int i = 0; i < 8; ++i)
                #pragma unroll
                for (int jj = 0; jj < 8; ++jj)
                    acc[i][jj] += a[i] * bq[jj];
        }
        __syncthreads();
    }
    #pragma unroll
    for (int i = 0; i < 8; ++i) {
        int row = bm0 + ty * 8 + i;
        size_t off = (size_t)row * 1024 + bn0 + tx * 8;
        float4 r0 = *(const float4*)&X[off];
        float4 r1 = *(const float4*)&X[off + 4];
        float4 o0 = make_float4(acc[i][0] + r0.x, acc[i][1] + r0.y,
                                acc[i][2] + r0.z, acc[i][3] + r0.w);
        float4 o1 = make_float4(acc[i][4] + r1.x, acc[i][5] + r1.y,
                                acc[i][6] + r1.z, acc[i][7] + r1.w);
        *(float4*)&V[off] = o0;
        *(float4*)&V[off + 4] = o1;
    }
}

// ----------------------------- LayerNorm (in-place) ------------------------
__global__ __launch_bounds__(256)
void ln_kernel(float* __restrict__ V, const float* __restrict__ gamma,
               const float* __restrict__ beta) {
    __shared__ float red[8];
    int row = blockIdx.x;
    int tid = threadIdx.x;
    float4 v = *(const float4*)&V[(size_t)row * 1024 + tid * 4];
    float s = v.x + v.y + v.z + v.w;
    float s2 = v.x * v.x + v.y * v.y + v.z * v.z + v.w * v.w;
    #pragma unroll
    for (int off = 32; off; off >>= 1) {
        s  += __shfl_xor(s, off, 64);
        s2 += __shfl_xor(s2, off, 64);
    }
    if ((tid & 63) == 0) { red[(tid >> 6) * 2] = s; red[(tid >> 6) * 2 + 1] = s2; }
    __syncthreads();
    s  = red[0] + red[2] + red[4] + red[6];
    s2 = red[1] + red[3] + red[5] + red[7];
    float mu = s * (1.f / 1024.f);
    float var = s2 * (1.f / 1024.f) - mu * mu;
    float rs = rsqrtf(var + 1e-6f);
    float4 g  = *(const float4*)&gamma[tid * 4];
    float4 be = *(const float4*)&beta[tid * 4];
    float4 o = make_float4((v.x - mu) * rs * g.x + be.x,
                           (v.y - mu) * rs * g.y + be.y,
                           (v.z - mu) * rs * g.z + be.z,
                           (v.w - mu) * rs * g.w + be.w);
    *(float4*)&V[(size_t)row * 1024 + tid * 4] = o;
}

extern "C" void kernel_launch(void* const* d_in, const int* in_sizes, int n_in,
                              void* d_out, int out_size, void* d_ws, size_t ws_size,
                              hipStream_t stream) {
    const float* x     = (const float*)d_in[0];
    const float* W_pe  = (const float*)d_in[1];
    const float* b_pe  = (const float*)d_in[2];
    const float* stt   = (const float*)d_in[3];
    const float* W_fc  = (const float*)d_in[4];
    const float* gamma = (const float*)d_in[5];
    const float* beta  = (const float*)d_in[6];
    float* out = (float*)d_out;

    char* ws = (char*)d_ws;
    float* avg  = (float*)ws;                                  // 64 MB
    float* conv = (float*)(ws + (size_t)64 * 1024 * 1024);     // 64 MB
    float* segs = (float*)(ws + (size_t)128 * 1024 * 1024);    // 1 MB

    seg_sum_kernel<<<1024, 256, 0, stream>>>(x, segs);
    avg_kernel<<<1024, 256, 0, stream>>>(x, segs, avg);
    conv_kernel<<<4096, 256, 0, stream>>>(avg, W_pe, b_pe, stt, conv);
    gemm_kernel<<<dim3(8, 128), 256, 0, stream>>>(conv, W_fc, x, out);
    ln_kernel<<<16384, 256, 0, stream>>>(out, gamma, beta);
}

// Round 2
// 328.843 us; speedup vs baseline: 2.0514x; 2.0514x over previous
//
#include <hip/hip_runtime.h>
#include <math.h>

// Problem constants (B,L,D,H,K) = (8, 2048, 1024, 16, 31)
#define BB 8
#define LL 2048
#define DD 1024
#define HH 16
#define DH 64          // D/H
#define KK 31
#define NSEG 32
#define SEGLEN 64      // LL/NSEG

#define TLEN 64        // tokens per conv block
#define WIN 94         // TLEN + KK - 1
#define WSTR 68        // win row stride (floats), keeps float4 alignment
#define PSTR 65        // pc row stride (floats), breaks bank collisions

typedef __attribute__((ext_vector_type(8))) short bf16x8;
typedef __attribute__((ext_vector_type(4))) float f32x4;
typedef __attribute__((ext_vector_type(8))) unsigned short u16x8;

__device__ __forceinline__ unsigned short f2bf(float f) {
    unsigned u = __float_as_uint(f);
    unsigned r = (u + 0x7fffu + ((u >> 16) & 1u)) >> 16;   // RNE
    return (unsigned short)r;
}

__device__ __forceinline__ void gload_lds16(const void* g, void* l) {
    __builtin_amdgcn_global_load_lds(
        (const __attribute__((address_space(1))) void*)g,
        (__attribute__((address_space(3))) void*)l, 16, 0, 0);
}

// ---------------- Pass 1a: per-segment sums (for parallel cumsum) ----------
__global__ __launch_bounds__(256)
void seg_sum_kernel(const float* __restrict__ x, float* __restrict__ segsum) {
    int g = blockIdx.x * 256 + threadIdx.x;   // B*NSEG*D threads
    int d = g & (DD - 1);
    int s = (g >> 10) & (NSEG - 1);
    int b = g >> 15;
    const float* p = x + (size_t)(b * LL + s * SEGLEN) * DD + d;
    float acc = 0.f;
    #pragma unroll 8
    for (int i = 0; i < SEGLEN; ++i) acc += p[(size_t)i * DD];
    segsum[g] = acc;   // layout [b][s][d] == flat g
}

// ---------------- Pass 1b: running mean avg[b,t,d] = cumsum/(t+1) ----------
__global__ __launch_bounds__(256)
void avg_kernel(const float* __restrict__ x, const float* __restrict__ segsum,
                float* __restrict__ avg) {
    int g = blockIdx.x * 256 + threadIdx.x;
    int d = g & (DD - 1);
    int s = (g >> 10) & (NSEG - 1);
    int b = g >> 15;
    float run = 0.f;
    const float* ss = segsum + ((size_t)b << 15) + d;
    for (int s2 = 0; s2 < s; ++s2) run += ss[s2 << 10];
    const float* p = x + (size_t)(b * LL + s * SEGLEN) * DD + d;
    float* q = avg + (size_t)(b * LL + s * SEGLEN) * DD + d;
    int t0 = s * SEGLEN;
    #pragma unroll 4
    for (int i = 0; i < SEGLEN; ++i) {
        run += p[(size_t)i * DD];
        q[(size_t)i * DD] = run / (float)(t0 + i + 1);
    }
}

// ------- Fused: pc = ci@W_pe+b_pe -> gated energy -> softmax -> local conv --
// Output written as bf16 (GEMM A-operand).
__global__ __launch_bounds__(256)
void conv_kernel(const float* __restrict__ avg, const float* __restrict__ W_pe,
                 const float* __restrict__ b_pe, const float* __restrict__ stt,
                 unsigned short* __restrict__ conv) {
    __shared__ float win[WIN * WSTR];
    __shared__ float wpe[64 * 64];
    __shared__ float pcs[TLEN * PSTR];

    int tid = threadIdx.x;
    int tile = blockIdx.x & 31;
    int bh = blockIdx.x >> 5;
    int b = bh >> 4, h = bh & 15;
    int t0 = tile * TLEN;

    for (int i = tid; i < 64 * 64; i += 256) {
        int j = i >> 6, k = i & 63;
        wpe[i] = (k < 2 * KK) ? W_pe[j * (2 * KK) + k] : 0.f;
    }
    const float* base = avg + (size_t)(b * LL) * DD + h * DH;
    for (int i = tid; i < WIN * DH; i += 256) {
        int r = i >> 6, j = i & 63;
        int g = t0 - (KK - 1) + r;
        win[r * WSTR + j] = (g >= 0) ? base[(size_t)g * DD + j] : 0.f;
    }
    __syncthreads();

    {   // pc = ci @ W_pe + b_pe  (4x4 micro-tile)
        int tx = tid & 15, ty = tid >> 4;
        int c0 = tx * 4, t4 = ty * 4;
        float acc[4][4];
        #pragma unroll
        for (int i = 0; i < 4; ++i)
            #pragma unroll
            for (int c = 0; c < 4; ++c)
                acc[i][c] = (c0 + c < 2 * KK) ? b_pe[c0 + c] : 0.f;
        for (int j = 0; j < 64; ++j) {
            float4 bv = *(const float4*)&wpe[j * 64 + c0];
            #pragma unroll
            for (int i = 0; i < 4; ++i) {
                float a = win[(t4 + i + (KK - 1)) * WSTR + j];
                acc[i][0] += a * bv.x; acc[i][1] += a * bv.y;
                acc[i][2] += a * bv.z; acc[i][3] += a * bv.w;
            }
        }
        #pragma unroll
        for (int i = 0; i < 4; ++i)
            #pragma unroll
            for (int c = 0; c < 4; ++c)
                pcs[(t4 + i) * PSTR + c0 + c] = acc[i][c];
    }
    __syncthreads();

    {   // softmax weights: energy = stt + sigmoid(gate)*dyn ; mask AFTER softmax
        int lane = tid & 63, w = tid >> 6;
        float sttk = (lane < KK) ? stt[h * KK + lane] : 0.f;
        for (int it = 0; it < 16; ++it) {
            int tok = w * 16 + it;
            float dyn  = pcs[tok * PSTR + lane];
            int gi = tok * PSTR + KK + ((lane < KK) ? lane : 0);
            float gate = pcs[gi];
            float en = (lane < KK) ? sttk + dyn / (1.f + __expf(-gate)) : -3.0e38f;
            float m = en;
            #pragma unroll
            for (int off = 32; off; off >>= 1) m = fmaxf(m, __shfl_xor(m, off, 64));
            float e = (lane < KK) ? __expf(en - m) : 0.f;
            float sum = e;
            #pragma unroll
            for (int off = 32; off; off >>= 1) sum += __shfl_xor(sum, off, 64);
            float wv = e / sum;
            if (t0 + tok + lane < KK - 1) wv = 0.f;
            if (lane < KK) pcs[tok * PSTR + lane] = wv;
        }
    }
    __syncthreads();

    {   // conv: out[tok][j] = sum_k w[tok][k] * ci[tok+k-30][j]  -> bf16
        int tok = tid >> 2;
        int jg = (tid & 3) * 16;
        float wreg[KK];
        #pragma unroll
        for (int k = 0; k < KK; ++k) wreg[k] = pcs[tok * PSTR + k];
        float acc[16];
        #pragma unroll
        for (int q = 0; q < 16; ++q) acc[q] = 0.f;
        for (int k = 0; k < KK; ++k) {
            const float* wr = &win[(tok + k) * WSTR + jg];
            float wk = wreg[k];
            #pragma unroll
            for (int q4 = 0; q4 < 4; ++q4) {
                float4 a = *(const float4*)&wr[q4 * 4];
                acc[q4 * 4 + 0] += wk * a.x; acc[q4 * 4 + 1] += wk * a.y;
                acc[q4 * 4 + 2] += wk * a.z; acc[q4 * 4 + 3] += wk * a.w;
            }
        }
        unsigned short* o = conv + (size_t)(b * LL + t0 + tok) * DD + h * DH + jg;
        u16x8 o0, o1;
        #pragma unroll
        for (int q = 0; q < 8; ++q) { o0[q] = f2bf(acc[q]); o1[q] = f2bf(acc[8 + q]); }
        *(u16x8*)&o[0] = o0;
        *(u16x8*)&o[8] = o1;
    }
}

// ----------------------- W_fc f32 -> bf16 cast (2MB) -----------------------
__global__ __launch_bounds__(256)
void cvt_kernel(const float* __restrict__ in, unsigned short* __restrict__ out) {
    int i = (blockIdx.x * 256 + threadIdx.x) * 4;
    float4 v = *(const float4*)&in[i];
    ushort4 o;
    o.x = f2bf(v.x); o.y = f2bf(v.y); o.z = f2bf(v.z); o.w = f2bf(v.w);
    *(ushort4*)&out[i] = o;
}

// -------- v = conv @ W_fc^T + x  (bf16 MFMA, m97 structure, 128x128) -------
// A: conv bf16 [16384][1024]; Bt: W_fc bf16 [1024][1024] ([n][k] == B^T)
__global__ __launch_bounds__(256)
void gemm_mfma_kernel(const unsigned short* __restrict__ A,
                      const unsigned short* __restrict__ Bt,
                      const float* __restrict__ X,
                      float* __restrict__ V)
{
    __shared__ short As[128 * 32];   // 8 KB, linear [row][k]
    __shared__ short Bs[128 * 32];   // 8 KB
    int tid = threadIdx.x;
    int wv = tid >> 6, ln = tid & 63;
    int bid = blockIdx.x;
    int bn0 = (bid & 7) * 128;
    int bm0 = (bid >> 3) * 128;
    int wr = wv >> 1, wc = wv & 1;

    // staging geometry: 8 chunks of 1KB per operand; wave wv owns chunks 2wv,2wv+1
    int c0 = wv * 2;
    int r0 = c0 * 16 + (ln >> 2);        // tile row for chunk c0
    int kc = (ln & 3) * 8;               // k column (bf16 elements)
    const unsigned short* gA0 = A  + (size_t)(bm0 + r0) * 1024 + kc;
    const unsigned short* gA1 = gA0 + (size_t)16 * 1024;
    const unsigned short* gB0 = Bt + (size_t)(bn0 + r0) * 1024 + kc;
    const unsigned short* gB1 = gB0 + (size_t)16 * 1024;
    short* lA0 = &As[c0 * 512];          // wave-uniform LDS base (byte off c0*1024)
    short* lA1 = &As[c0 * 512 + 512];
    short* lB0 = &Bs[c0 * 512];
    short* lB1 = &Bs[c0 * 512 + 512];

    f32x4 acc[4][4] = {};
    int arow = wr * 64 + (ln & 15);
    int brow = wc * 64 + (ln & 15);
    int kb = (ln >> 4) * 8;

    for (int kt = 0; kt < 1024; kt += 32) {
        gload_lds16(gA0 + kt, lA0);
        gload_lds16(gA1 + kt, lA1);
        gload_lds16(gB0 + kt, lB0);
        gload_lds16(gB1 + kt, lB1);
        __syncthreads();
        bf16x8 af[4], bfr[4];
        #pragma unroll
        for (int m = 0; m < 4; ++m)
            af[m] = *(const bf16x8*)&As[(arow + m * 16) * 32 + kb];
        #pragma unroll
        for (int n = 0; n < 4; ++n)
            bfr[n] = *(const bf16x8*)&Bs[(brow + n * 16) * 32 + kb];
        #pragma unroll
        for (int m = 0; m < 4; ++m)
            #pragma unroll
            for (int n = 0; n < 4; ++n)
                acc[m][n] = __builtin_amdgcn_mfma_f32_16x16x32_bf16(
                    af[m], bfr[n], acc[m][n], 0, 0, 0);
        __syncthreads();
    }

    // epilogue: += residual, write f32
    int rbase = bm0 + wr * 64 + (ln >> 4) * 4;
    int cbase = bn0 + wc * 64 + (ln & 15);
    #pragma unroll
    for (int m = 0; m < 4; ++m) {
        #pragma unroll
        for (int r = 0; r < 4; ++r) {
            int row = rbase + m * 16 + r;
            size_t off = (size_t)row * 1024 + cbase;
            #pragma unroll
            for (int n = 0; n < 4; ++n)
                V[off + n * 16] = acc[m][n][r] + X[off + n * 16];
        }
    }
}

// ----------------------------- LayerNorm (in-place) ------------------------
__global__ __launch_bounds__(256)
void ln_kernel(float* __restrict__ V, const float* __restrict__ gamma,
               const float* __restrict__ beta) {
    __shared__ float red[8];
    int row = blockIdx.x;
    int tid = threadIdx.x;
    float4 v = *(const float4*)&V[(size_t)row * 1024 + tid * 4];
    float s = v.x + v.y + v.z + v.w;
    float s2 = v.x * v.x + v.y * v.y + v.z * v.z + v.w * v.w;
    #pragma unroll
    for (int off = 32; off; off >>= 1) {
        s  += __shfl_xor(s, off, 64);
        s2 += __shfl_xor(s2, off, 64);
    }
    if ((tid & 63) == 0) { red[(tid >> 6) * 2] = s; red[(tid >> 6) * 2 + 1] = s2; }
    __syncthreads();
    s  = red[0] + red[2] + red[4] + red[6];
    s2 = red[1] + red[3] + red[5] + red[7];
    float mu = s * (1.f / 1024.f);
    float var = s2 * (1.f / 1024.f) - mu * mu;
    float rs = rsqrtf(var + 1e-6f);
    float4 g  = *(const float4*)&gamma[tid * 4];
    float4 be = *(const float4*)&beta[tid * 4];
    float4 o = make_float4((v.x - mu) * rs * g.x + be.x,
                           (v.y - mu) * rs * g.y + be.y,
                           (v.z - mu) * rs * g.z + be.z,
                           (v.w - mu) * rs * g.w + be.w);
    *(float4*)&V[(size_t)row * 1024 + tid * 4] = o;
}

extern "C" void kernel_launch(void* const* d_in, const int* in_sizes, int n_in,
                              void* d_out, int out_size, void* d_ws, size_t ws_size,
                              hipStream_t stream) {
    const float* x     = (const float*)d_in[0];
    const float* W_pe  = (const float*)d_in[1];
    const float* b_pe  = (const float*)d_in[2];
    const float* stt   = (const float*)d_in[3];
    const float* W_fc  = (const float*)d_in[4];
    const float* gamma = (const float*)d_in[5];
    const float* beta  = (const float*)d_in[6];
    float* out = (float*)d_out;

    char* ws = (char*)d_ws;
    float*          avg   = (float*)ws;                                   // 64 MB
    unsigned short* convb = (unsigned short*)(ws + (size_t)64  * 1024 * 1024); // 32 MB
    unsigned short* wfcb  = (unsigned short*)(ws + (size_t)96  * 1024 * 1024); //  2 MB
    float*          segs  = (float*)(ws + (size_t)100 * 1024 * 1024);     //  1 MB

    seg_sum_kernel<<<1024, 256, 0, stream>>>(x, segs);
    avg_kernel<<<1024, 256, 0, stream>>>(x, segs, avg);
    cvt_kernel<<<1024, 256, 0, stream>>>(W_fc, wfcb);
    conv_kernel<<<4096, 256, 0, stream>>>(avg, W_pe, b_pe, stt, convb);
    gemm_mfma_kernel<<<1024, 256, 0, stream>>>(convb, wfcb, x, out);
    ln_kernel<<<16384, 256, 0, stream>>>(out, gamma, beta);
}

// Round 3
// 201.198 us; speedup vs baseline: 3.3528x; 1.6344x over previous
//
#include <hip/hip_runtime.h>
#include <math.h>

// Problem constants (B,L,D,H,K) = (8, 2048, 1024, 16, 31)
#define BB 8
#define LL 2048
#define DD 1024
#define HH 16
#define DH 64          // D/H
#define KK 31
#define NSEG 32
#define SEGLEN 64      // LL/NSEG

#define TLEN 64        // tokens per conv block
#define WIN 94         // TLEN + KK - 1
#define WSTR 68        // win row stride (floats): float4-aligned, bank-staggered
#define PCS 68         // pcs row stride (u16): 136B = 8B-aligned, +2 bank rotate

typedef __attribute__((ext_vector_type(8))) short bf16x8;
typedef __attribute__((ext_vector_type(4))) float f32x4;
typedef __attribute__((ext_vector_type(8))) unsigned short u16x8;

__device__ __forceinline__ unsigned short f2bf(float f) {
    unsigned u = __float_as_uint(f);
    unsigned r = (u + 0x7fffu + ((u >> 16) & 1u)) >> 16;   // RNE
    return (unsigned short)r;
}
__device__ __forceinline__ float bf2f(unsigned short s) {
    return __uint_as_float(((unsigned)s) << 16);
}

__device__ __forceinline__ void gload_lds16(const void* g, void* l) {
    __builtin_amdgcn_global_load_lds(
        (const __attribute__((address_space(1))) void*)g,
        (__attribute__((address_space(3))) void*)l, 16, 0, 0);
}

// ---------------- Pass 1a: per-segment sums (for parallel cumsum) ----------
__global__ __launch_bounds__(256)
void seg_sum_kernel(const float* __restrict__ x, float* __restrict__ segsum) {
    int g = blockIdx.x * 256 + threadIdx.x;   // B*NSEG*D threads
    int d = g & (DD - 1);
    int s = (g >> 10) & (NSEG - 1);
    int b = g >> 15;
    const float* p = x + (size_t)(b * LL + s * SEGLEN) * DD + d;
    float acc = 0.f;
    #pragma unroll 8
    for (int i = 0; i < SEGLEN; ++i) acc += p[(size_t)i * DD];
    segsum[g] = acc;   // layout [b][s][d] == flat g
}

// ---------------- Pass 1b: running mean avg[b,t,d] = cumsum/(t+1) ----------
__global__ __launch_bounds__(256)
void avg_kernel(const float* __restrict__ x, const float* __restrict__ segsum,
                float* __restrict__ avg) {
    int g = blockIdx.x * 256 + threadIdx.x;
    int d = g & (DD - 1);
    int s = (g >> 10) & (NSEG - 1);
    int b = g >> 15;
    float run = 0.f;
    const float* ss = segsum + ((size_t)b << 15) + d;
    for (int s2 = 0; s2 < s; ++s2) run += ss[s2 << 10];
    const float* p = x + (size_t)(b * LL + s * SEGLEN) * DD + d;
    float* q = avg + (size_t)(b * LL + s * SEGLEN) * DD + d;
    int t0 = s * SEGLEN;
    #pragma unroll 4
    for (int i = 0; i < SEGLEN; ++i) {
        run += p[(size_t)i * DD];
        q[(size_t)i * DD] = run / (float)(t0 + i + 1);
    }
}

// ------- Fused: pc = ci@W_pe+b_pe -> gated energy -> softmax -> local conv --
// win f32 in LDS; W_pe served from L1; pc/weights bf16 in LDS; out bf16.
__global__ __launch_bounds__(256, 4)
void conv_kernel(const float* __restrict__ avg, const float* __restrict__ W_pe,
                 const float* __restrict__ b_pe, const float* __restrict__ stt,
                 unsigned short* __restrict__ conv) {
    __shared__ float win[WIN * WSTR];            // 25568 B
    __shared__ unsigned short pcs[TLEN * PCS];   //  8704 B

    int tid = threadIdx.x;
    int tile = blockIdx.x & 31;
    int bh = blockIdx.x >> 5;
    int b = bh >> 4, h = bh & 15;
    int t0 = tile * TLEN;

    // stage ci window (float4-vectorized, coalesced)
    const float* base = avg + (size_t)(b * LL) * DD + h * DH;
    for (int i = tid; i < WIN * 16; i += 256) {
        int r = i >> 4, c4 = (i & 15) * 4;
        int g = t0 - (KK - 1) + r;
        float4 v = (g >= 0) ? *(const float4*)&base[(size_t)g * DD + c4]
                            : make_float4(0.f, 0.f, 0.f, 0.f);
        *(float4*)&win[r * WSTR + c4] = v;
    }
    __syncthreads();

    {   // pc = ci @ W_pe + b_pe : 4 tokens x 4 cols per thread, k-chunks of 4
        int tx = tid & 15, ty = tid >> 4;
        int c0 = (tx == 15) ? 58 : tx * 4;     // last chunk overlaps (dup writes ok)
        int t4 = ty * 4;
        float acc[4][4];
        #pragma unroll
        for (int i = 0; i < 4; ++i)
            #pragma unroll
            for (int c = 0; c < 4; ++c)
                acc[i][c] = b_pe[c0 + c];
        for (int j4 = 0; j4 < 64; j4 += 4) {
            float4 a[4];
            #pragma unroll
            for (int i = 0; i < 4; ++i)
                a[i] = *(const float4*)&win[(t4 + i + KK - 1) * WSTR + j4];
            float w[4][4];
            #pragma unroll
            for (int jj = 0; jj < 4; ++jj) {
                float2 lo = *(const float2*)&W_pe[(j4 + jj) * 62 + c0];
                float2 hi = *(const float2*)&W_pe[(j4 + jj) * 62 + c0 + 2];
                w[jj][0] = lo.x; w[jj][1] = lo.y; w[jj][2] = hi.x; w[jj][3] = hi.y;
            }
            #pragma unroll
            for (int i = 0; i < 4; ++i) {
                float ai[4] = {a[i].x, a[i].y, a[i].z, a[i].w};
                #pragma unroll
                for (int jj = 0; jj < 4; ++jj)
                    #pragma unroll
                    for (int c = 0; c < 4; ++c)
                        acc[i][c] += ai[jj] * w[jj][c];
            }
        }
        #pragma unroll
        for (int i = 0; i < 4; ++i) {
            ushort2 p0, p1;
            p0.x = f2bf(acc[i][0]); p0.y = f2bf(acc[i][1]);
            p1.x = f2bf(acc[i][2]); p1.y = f2bf(acc[i][3]);
            *(ushort2*)&pcs[(t4 + i) * PCS + c0]     = p0;
            *(ushort2*)&pcs[(t4 + i) * PCS + c0 + 2] = p1;
        }
    }
    __syncthreads();

    {   // softmax: 2 tokens per wave-iter (31-lane halves, width-32 reduce)
        int lane = tid & 63, w = tid >> 6;
        int half = lane >> 5;
        int k = lane & 31;
        int kc = (k < KK) ? k : 0;
        float sttk = stt[h * KK + kc];
        for (int it = 0; it < 8; ++it) {
            int tok = w * 16 + it * 2 + half;
            float dyn  = bf2f(pcs[tok * PCS + kc]);
            float gate = bf2f(pcs[tok * PCS + KK + kc]);
            float en = (k < KK) ? sttk + dyn / (1.f + __expf(-gate)) : -3.0e38f;
            float m = en;
            #pragma unroll
            for (int off = 16; off; off >>= 1) m = fmaxf(m, __shfl_xor(m, off, 64));
            float e = (k < KK) ? __expf(en - m) : 0.f;
            float sum = e;
            #pragma unroll
            for (int off = 16; off; off >>= 1) sum += __shfl_xor(sum, off, 64);
            float wv = e / sum;
            if (t0 + tok + k < KK - 1) wv = 0.f;   // causal mask (post-softmax)
            if (k < KK) pcs[tok * PCS + k] = f2bf(wv);
        }
    }
    __syncthreads();

    {   // conv: out[tok][j] = sum_k w[tok][k] * ci[tok+k-30][j]  -> bf16
        int tok = tid >> 2;
        int jg = (tid & 3) * 16;
        float wreg[KK];
        #pragma unroll
        for (int k = 0; k < KK; ++k) wreg[k] = bf2f(pcs[tok * PCS + k]);
        float acc[16];
        #pragma unroll
        for (int q = 0; q < 16; ++q) acc[q] = 0.f;
        for (int k = 0; k < KK; ++k) {
            const float* wr = &win[(tok + k) * WSTR + jg];
            float wk = wreg[k];
            #pragma unroll
            for (int q4 = 0; q4 < 4; ++q4) {
                float4 a = *(const float4*)&wr[q4 * 4];
                acc[q4 * 4 + 0] += wk * a.x; acc[q4 * 4 + 1] += wk * a.y;
                acc[q4 * 4 + 2] += wk * a.z; acc[q4 * 4 + 3] += wk * a.w;
            }
        }
        unsigned short* o = conv + (size_t)(b * LL + t0 + tok) * DD + h * DH + jg;
        u16x8 o0, o1;
        #pragma unroll
        for (int q = 0; q < 8; ++q) { o0[q] = f2bf(acc[q]); o1[q] = f2bf(acc[8 + q]); }
        *(u16x8*)&o[0] = o0;
        *(u16x8*)&o[8] = o1;
    }
}

// ----------------------- W_fc f32 -> bf16 cast (2MB) -----------------------
__global__ __launch_bounds__(256)
void cvt_kernel(const float* __restrict__ in, unsigned short* __restrict__ out) {
    int i = (blockIdx.x * 256 + threadIdx.x) * 4;
    float4 v = *(const float4*)&in[i];
    ushort4 o;
    o.x = f2bf(v.x); o.y = f2bf(v.y); o.z = f2bf(v.z); o.w = f2bf(v.w);
    *(ushort4*)&out[i] = o;
}

// -------- v = conv @ W_fc^T + x  (bf16 MFMA, m97 structure, 128x128) -------
__global__ __launch_bounds__(256)
void gemm_mfma_kernel(const unsigned short* __restrict__ A,
                      const unsigned short* __restrict__ Bt,
                      const float* __restrict__ X,
                      float* __restrict__ V)
{
    __shared__ short As[128 * 32];   // 8 KB, linear [row][k]
    __shared__ short Bs[128 * 32];   // 8 KB
    int tid = threadIdx.x;
    int wv = tid >> 6, ln = tid & 63;
    int bid = blockIdx.x;
    int bn0 = (bid & 7) * 128;
    int bm0 = (bid >> 3) * 128;
    int wr = wv >> 1, wc = wv & 1;

    int c0 = wv * 2;
    int r0 = c0 * 16 + (ln >> 2);
    int kc = (ln & 3) * 8;
    const unsigned short* gA0 = A  + (size_t)(bm0 + r0) * 1024 + kc;
    const unsigned short* gA1 = gA0 + (size_t)16 * 1024;
    const unsigned short* gB0 = Bt + (size_t)(bn0 + r0) * 1024 + kc;
    const unsigned short* gB1 = gB0 + (size_t)16 * 1024;
    short* lA0 = &As[c0 * 512];
    short* lA1 = &As[c0 * 512 + 512];
    short* lB0 = &Bs[c0 * 512];
    short* lB1 = &Bs[c0 * 512 + 512];

    f32x4 acc[4][4] = {};
    int arow = wr * 64 + (ln & 15);
    int brow = wc * 64 + (ln & 15);
    int kb = (ln >> 4) * 8;

    for (int kt = 0; kt < 1024; kt += 32) {
        gload_lds16(gA0 + kt, lA0);
        gload_lds16(gA1 + kt, lA1);
        gload_lds16(gB0 + kt, lB0);
        gload_lds16(gB1 + kt, lB1);
        __syncthreads();
        bf16x8 af[4], bfr[4];
        #pragma unroll
        for (int m = 0; m < 4; ++m)
            af[m] = *(const bf16x8*)&As[(arow + m * 16) * 32 + kb];
        #pragma unroll
        for (int n = 0; n < 4; ++n)
            bfr[n] = *(const bf16x8*)&Bs[(brow + n * 16) * 32 + kb];
        #pragma unroll
        for (int m = 0; m < 4; ++m)
            #pragma unroll
            for (int n = 0; n < 4; ++n)
                acc[m][n] = __builtin_amdgcn_mfma_f32_16x16x32_bf16(
                    af[m], bfr[n], acc[m][n], 0, 0, 0);
        __syncthreads();
    }

    int rbase = bm0 + wr * 64 + (ln >> 4) * 4;
    int cbase = bn0 + wc * 64 + (ln & 15);
    #pragma unroll
    for (int m = 0; m < 4; ++m) {
        #pragma unroll
        for (int r = 0; r < 4; ++r) {
            int row = rbase + m * 16 + r;
            size_t off = (size_t)row * 1024 + cbase;
            #pragma unroll
            for (int n = 0; n < 4; ++n)
                V[off + n * 16] = acc[m][n][r] + X[off + n * 16];
        }
    }
}

// ----------------------------- LayerNorm (in-place) ------------------------
__global__ __launch_bounds__(256)
void ln_kernel(float* __restrict__ V, const float* __restrict__ gamma,
               const float* __restrict__ beta) {
    __shared__ float red[8];
    int row = blockIdx.x;
    int tid = threadIdx.x;
    float4 v = *(const float4*)&V[(size_t)row * 1024 + tid * 4];
    float s = v.x + v.y + v.z + v.w;
    float s2 = v.x * v.x + v.y * v.y + v.z * v.z + v.w * v.w;
    #pragma unroll
    for (int off = 32; off; off >>= 1) {
        s  += __shfl_xor(s, off, 64);
        s2 += __shfl_xor(s2, off, 64);
    }
    if ((tid & 63) == 0) { red[(tid >> 6) * 2] = s; red[(tid >> 6) * 2 + 1] = s2; }
    __syncthreads();
    s  = red[0] + red[2] + red[4] + red[6];
    s2 = red[1] + red[3] + red[5] + red[7];
    float mu = s * (1.f / 1024.f);
    float var = s2 * (1.f / 1024.f) - mu * mu;
    float rs = rsqrtf(var + 1e-6f);
    float4 g  = *(const float4*)&gamma[tid * 4];
    float4 be = *(const float4*)&beta[tid * 4];
    float4 o = make_float4((v.x - mu) * rs * g.x + be.x,
                           (v.y - mu) * rs * g.y + be.y,
                           (v.z - mu) * rs * g.z + be.z,
                           (v.w - mu) * rs * g.w + be.w);
    *(float4*)&V[(size_t)row * 1024 + tid * 4] = o;
}

extern "C" void kernel_launch(void* const* d_in, const int* in_sizes, int n_in,
                              void* d_out, int out_size, void* d_ws, size_t ws_size,
                              hipStream_t stream) {
    const float* x     = (const float*)d_in[0];
    const float* W_pe  = (const float*)d_in[1];
    const float* b_pe  = (const float*)d_in[2];
    const float* stt   = (const float*)d_in[3];
    const float* W_fc  = (const float*)d_in[4];
    const float* gamma = (const float*)d_in[5];
    const float* beta  = (const float*)d_in[6];
    float* out = (float*)d_out;

    char* ws = (char*)d_ws;
    float*          avg   = (float*)ws;                                        // 64 MB
    unsigned short* convb = (unsigned short*)(ws + (size_t)64  * 1024 * 1024); // 32 MB
    unsigned short* wfcb  = (unsigned short*)(ws + (size_t)96  * 1024 * 1024); //  2 MB
    float*          segs  = (float*)(ws + (size_t)100 * 1024 * 1024);          //  1 MB

    seg_sum_kernel<<<1024, 256, 0, stream>>>(x, segs);
    avg_kernel<<<1024, 256, 0, stream>>>(x, segs, avg);
    cvt_kernel<<<1024, 256, 0, stream>>>(W_fc, wfcb);
    conv_kernel<<<4096, 256, 0, stream>>>(avg, W_pe, b_pe, stt, convb);
    gemm_mfma_kernel<<<1024, 256, 0, stream>>>(convb, wfcb, x, out);
    ln_kernel<<<16384, 256, 0, stream>>>(out, gamma, beta);
}

// Round 5
// 180.796 us; speedup vs baseline: 3.7312x; 1.1128x over previous
//
#include <hip/hip_runtime.h>
#include <math.h>

// Problem constants (B,L,D,H,K) = (8, 2048, 1024, 16, 31)
#define BB 8
#define LL 2048
#define DD 1024
#define HH 16
#define DH 64          // D/H
#define KK 31
#define NSEG 32
#define SEGLEN 64      // LL/NSEG

#define TLEN 64        // tokens per conv block
#define PSTRIDE 72     // pcs row stride (u16), 144B, 16B-aligned
#define WBSTR 104      // wband row stride (u16), 208B, 16B-aligned
#define WPESTR 72      // wpeT row stride (u16), 144B, 16B-aligned
#define TSTR 104       // winT row stride (u16), 208B, 16B-aligned

typedef __attribute__((ext_vector_type(8))) short bf16x8;
typedef __attribute__((ext_vector_type(4))) float f32x4;
typedef __attribute__((ext_vector_type(8))) unsigned short u16x8;

__device__ __forceinline__ unsigned short f2bf(float f) {
    unsigned u = __float_as_uint(f);
    unsigned r = (u + 0x7fffu + ((u >> 16) & 1u)) >> 16;   // RNE
    return (unsigned short)r;
}
__device__ __forceinline__ float bf2f(unsigned short s) {
    return __uint_as_float(((unsigned)s) << 16);
}

__device__ __forceinline__ void gload_lds16(const void* g, void* l) {
    __builtin_amdgcn_global_load_lds(
        (const __attribute__((address_space(1))) void*)g,
        (__attribute__((address_space(3))) void*)l, 16, 0, 0);
}

// ---------------- Pass 1a: per-segment sums (for parallel cumsum) ----------
__global__ __launch_bounds__(256)
void seg_sum_kernel(const float* __restrict__ x, float* __restrict__ segsum) {
    int g = blockIdx.x * 256 + threadIdx.x;   // B*NSEG*D threads
    int d = g & (DD - 1);
    int s = (g >> 10) & (NSEG - 1);
    int b = g >> 15;
    const float* p = x + (size_t)(b * LL + s * SEGLEN) * DD + d;
    float acc = 0.f;
    #pragma unroll 8
    for (int i = 0; i < SEGLEN; ++i) acc += p[(size_t)i * DD];
    segsum[g] = acc;   // layout [b][s][d] == flat g
}

// ------------- Pass 1b: running mean avg (bf16 out) ------------------------
__global__ __launch_bounds__(256)
void avg_kernel(const float* __restrict__ x, const float* __restrict__ segsum,
                unsigned short* __restrict__ avg) {
    int g = blockIdx.x * 256 + threadIdx.x;
    int d = g & (DD - 1);
    int s = (g >> 10) & (NSEG - 1);
    int b = g >> 15;
    float run = 0.f;
    const float* ss = segsum + ((size_t)b << 15) + d;
    for (int s2 = 0; s2 < s; ++s2) run += ss[s2 << 10];
    const float* p = x + (size_t)(b * LL + s * SEGLEN) * DD + d;
    unsigned short* q = avg + (size_t)(b * LL + s * SEGLEN) * DD + d;
    int t0 = s * SEGLEN;
    #pragma unroll 4
    for (int i = 0; i < SEGLEN; ++i) {
        run += p[(size_t)i * DD];
        q[(size_t)i * DD] = f2bf(run / (float)(t0 + i + 1));
    }
}

// ------- Fused: pc = ci@W_pe+b_pe -> gated energy -> softmax -> local conv --
// All-MFMA. winS: subtiled token rows (A of pc). winT: transposed window
// (B of conv, plain row reads — no tr instruction). wub: wpeT then wband.
__global__ __launch_bounds__(256, 3)
void conv_kernel(const unsigned short* __restrict__ avgb,
                 const float* __restrict__ W_pe,
                 const float* __restrict__ b_pe, const float* __restrict__ stt,
                 unsigned short* __restrict__ conv) {
    __shared__ __align__(16) unsigned short winS[4 * 16 * 64];   //  8192 B
    __shared__ __align__(16) unsigned short winT[64 * TSTR];     // 13312 B
    __shared__ __align__(16) unsigned short wub[64 * WBSTR];     // 13312 B
    __shared__ __align__(16) unsigned short pcs[64 * PSTRIDE];   //  9216 B

    int tid = threadIdx.x;
    int tile = blockIdx.x & 31;
    int bh = blockIdx.x >> 5;
    int b = bh >> 4, h = bh & 15;
    int t0 = tile * TLEN;
    int wv = tid >> 6, ln = tid & 63;
    int g = ln >> 4, li = ln & 15;

    // ---- phase 0: stage window.  winT[col][p] = win[p][col] (96 rows);
    //      winS subtiled [jq][kr][4][16] for token rows 30..93 (local q=p-30).
    const unsigned short* basep = avgb + (size_t)(b * LL) * DD + h * DH;
    {
        int es = tid & 7;                      // de-conflict write order
        for (int i = tid; i < 96 * 8; i += 256) {
            int r = i >> 3, c0 = (i & 7) * 8;
            int gr = t0 - (KK - 1) + r;
            u16x8 v = {};
            if (gr >= 0 && r < 94) v = *(const u16x8*)&basep[(size_t)gr * DD + c0];
            #pragma unroll
            for (int ee = 0; ee < 8; ++ee) {
                int e = ee ^ es;
                winT[(c0 + e) * TSTR + r] = v[e];
            }
            if (r >= 30) {                     // token row q = r-30 into winS
                int q = r - 30;
                int jq = c0 >> 4, cc = c0 & 15;
                *(u16x8*)&winS[jq * 1024 + (q >> 2) * 64 + (q & 3) * 16 + cc] = v;
            }
        }
    }
    {   // stage wpeT[c][d] = bf16(W_pe[d][c]) into wub (union region)
        int d = tid & 63, cq = tid >> 6;
        const float* wrow = W_pe + d * (2 * KK);
        #pragma unroll
        for (int u = 0; u < 8; ++u) {
            int c = cq * 16 + u * 2;
            float fx = 0.f, fy = 0.f;
            if (c < 61) { float2 f = *(const float2*)&wrow[c]; fx = f.x; fy = f.y; }
            wub[c * WPESTR + d] = f2bf(fx);
            wub[(c + 1) * WPESTR + d] = f2bf(fy);
        }
    }
    __syncthreads();

    // ---- phase 1: pc = ci @ W_pe + b_pe via MFMA (wave wv = m-tile wv) ----
    {
        int q = wv * 16 + li;                  // local token row
        int pk = (q >> 2) * 64 + (q & 3) * 16;
        int jq0 = g >> 1, cc = (g & 1) * 8;
        bf16x8 a0 = *(const bf16x8*)&winS[jq0 * 1024 + pk + cc];
        bf16x8 a1 = *(const bf16x8*)&winS[(jq0 + 2) * 1024 + pk + cc];
        f32x4 acc[4];
        #pragma unroll
        for (int n = 0; n < 4; ++n) {
            int c = n * 16 + li;
            bf16x8 b0 = *(const bf16x8*)&wub[c * WPESTR + g * 8];
            bf16x8 b1 = *(const bf16x8*)&wub[c * WPESTR + 32 + g * 8];
            f32x4 z = {0.f, 0.f, 0.f, 0.f};
            z = __builtin_amdgcn_mfma_f32_16x16x32_bf16(a0, b0, z, 0, 0, 0);
            z = __builtin_amdgcn_mfma_f32_16x16x32_bf16(a1, b1, z, 0, 0, 0);
            acc[n] = z;
        }
        __syncthreads();   // wpeT reads done; wub becomes wband below
        #pragma unroll
        for (int n = 0; n < 4; ++n) {
            int c = n * 16 + li;
            float bp = (c < 2 * KK) ? b_pe[c] : 0.f;
            #pragma unroll
            for (int r = 0; r < 4; ++r)
                pcs[(wv * 16 + g * 4 + r) * PSTRIDE + c] = f2bf(acc[n][r] + bp);
        }
    }

    // ---- phase 2: zero wband ----
    for (int i = tid; i < 64 * WBSTR / 8; i += 256) {
        u16x8 z = {};
        *(u16x8*)&wub[i * 8] = z;
    }
    __syncthreads();

    // ---- phase 3: softmax -> scatter weights into banded wband ----
    {
        int half = ln >> 5, k = ln & 31;
        int kc = (k < KK) ? k : 0;
        float sttk = stt[h * KK + kc];
        for (int it = 0; it < 8; ++it) {
            int tok = wv * 16 + it * 2 + half;
            float dyn  = bf2f(pcs[tok * PSTRIDE + kc]);
            float gate = bf2f(pcs[tok * PSTRIDE + KK + kc]);
            float en = (k < KK) ? sttk + dyn / (1.f + __expf(-gate)) : -3.0e38f;
            float m = en;
            #pragma unroll
            for (int off = 16; off; off >>= 1) m = fmaxf(m, __shfl_xor(m, off, 64));
            float e = (k < KK) ? __expf(en - m) : 0.f;
            float sum = e;
            #pragma unroll
            for (int off = 16; off; off >>= 1) sum += __shfl_xor(sum, off, 64);
            float wvl = e / sum;
            if (k < KK && t0 + tok + k >= KK - 1)
                wub[tok * WBSTR + tok + k] = f2bf(wvl);   // wband[tok][tok+k]
        }
    }
    __syncthreads();

    // ---- phase 4: conv out = wband @ win via MFMA (B from winT rows) ----
    {
        bf16x8 wa0 = *(const bf16x8*)&wub[(wv * 16 + li) * WBSTR + g * 8];
        bf16x8 wa1 = *(const bf16x8*)&wub[(wv * 16 + li) * WBSTR + 32 + g * 8];
        bf16x8 wa2 = *(const bf16x8*)&wub[(wv * 16 + li) * WBSTR + 64 + g * 8];
        f32x4 acc[4];
        #pragma unroll
        for (int n = 0; n < 4; ++n) {
            int c = n * 16 + li;
            bf16x8 b0 = *(const bf16x8*)&winT[c * TSTR + g * 8];
            bf16x8 b1 = *(const bf16x8*)&winT[c * TSTR + 32 + g * 8];
            bf16x8 b2 = *(const bf16x8*)&winT[c * TSTR + 64 + g * 8];
            f32x4 z = {0.f, 0.f, 0.f, 0.f};
            z = __builtin_amdgcn_mfma_f32_16x16x32_bf16(wa0, b0, z, 0, 0, 0);
            z = __builtin_amdgcn_mfma_f32_16x16x32_bf16(wa1, b1, z, 0, 0, 0);
            z = __builtin_amdgcn_mfma_f32_16x16x32_bf16(wa2, b2, z, 0, 0, 0);
            acc[n] = z;
        }
        #pragma unroll
        for (int n = 0; n < 4; ++n)
            #pragma unroll
            for (int r = 0; r < 4; ++r)
                pcs[(wv * 16 + g * 4 + r) * PSTRIDE + n * 16 + li] =
                    f2bf(acc[n][r]);
    }
    __syncthreads();

    // ---- phase 5: coalesced store ----
    {
        int tok = tid >> 2, j0 = (tid & 3) * 16;
        u16x8 v0 = *(const u16x8*)&pcs[tok * PSTRIDE + j0];
        u16x8 v1 = *(const u16x8*)&pcs[tok * PSTRIDE + j0 + 8];
        unsigned short* o = conv + (size_t)(b * LL + t0 + tok) * DD + h * DH + j0;
        *(u16x8*)&o[0] = v0;
        *(u16x8*)&o[8] = v1;
    }
}

// ----------------------- W_fc f32 -> bf16 cast (2MB) -----------------------
__global__ __launch_bounds__(256)
void cvt_kernel(const float* __restrict__ in, unsigned short* __restrict__ out) {
    int i = (blockIdx.x * 256 + threadIdx.x) * 4;
    float4 v = *(const float4*)&in[i];
    ushort4 o;
    o.x = f2bf(v.x); o.y = f2bf(v.y); o.z = f2bf(v.z); o.w = f2bf(v.w);
    *(ushort4*)&out[i] = o;
}

// -------- v = conv @ W_fc^T + x  (bf16 MFMA, 128x128, XCD swizzle) ---------
__global__ __launch_bounds__(256)
void gemm_mfma_kernel(const unsigned short* __restrict__ A,
                      const unsigned short* __restrict__ Bt,
                      const float* __restrict__ X,
                      float* __restrict__ V)
{
    __shared__ short As[128 * 32];   // 8 KB, linear [row][k]
    __shared__ short Bs[128 * 32];   // 8 KB
    int tid = threadIdx.x;
    int wv = tid >> 6, ln = tid & 63;
    int bid = blockIdx.x;
    int nbid = (bid & 7) * 128 + (bid >> 3);   // XCD-contiguous chunks
    int bn0 = (nbid & 7) * 128;
    int bm0 = (nbid >> 3) * 128;
    int wr = wv >> 1, wc = wv & 1;

    int c0 = wv * 2;
    int r0 = c0 * 16 + (ln >> 2);
    int kc = (ln & 3) * 8;
    const unsigned short* gA0 = A  + (size_t)(bm0 + r0) * 1024 + kc;
    const unsigned short* gA1 = gA0 + (size_t)16 * 1024;
    const unsigned short* gB0 = Bt + (size_t)(bn0 + r0) * 1024 + kc;
    const unsigned short* gB1 = gB0 + (size_t)16 * 1024;
    short* lA0 = &As[c0 * 512];
    short* lA1 = &As[c0 * 512 + 512];
    short* lB0 = &Bs[c0 * 512];
    short* lB1 = &Bs[c0 * 512 + 512];

    f32x4 acc[4][4] = {};
    int arow = wr * 64 + (ln & 15);
    int brow = wc * 64 + (ln & 15);
    int kb = (ln >> 4) * 8;

    for (int kt = 0; kt < 1024; kt += 32) {
        gload_lds16(gA0 + kt, lA0);
        gload_lds16(gA1 + kt, lA1);
        gload_lds16(gB0 + kt, lB0);
        gload_lds16(gB1 + kt, lB1);
        __syncthreads();
        bf16x8 af[4], bfr[4];
        #pragma unroll
        for (int m = 0; m < 4; ++m)
            af[m] = *(const bf16x8*)&As[(arow + m * 16) * 32 + kb];
        #pragma unroll
        for (int n = 0; n < 4; ++n)
            bfr[n] = *(const bf16x8*)&Bs[(brow + n * 16) * 32 + kb];
        #pragma unroll
        for (int m = 0; m < 4; ++m)
            #pragma unroll
            for (int n = 0; n < 4; ++n)
                acc[m][n] = __builtin_amdgcn_mfma_f32_16x16x32_bf16(
                    af[m], bfr[n], acc[m][n], 0, 0, 0);
        __syncthreads();
    }

    int rbase = bm0 + wr * 64 + (ln >> 4) * 4;
    int cbase = bn0 + wc * 64 + (ln & 15);
    #pragma unroll
    for (int m = 0; m < 4; ++m) {
        #pragma unroll
        for (int r = 0; r < 4; ++r) {
            int row = rbase + m * 16 + r;
            size_t off = (size_t)row * 1024 + cbase;
            #pragma unroll
            for (int n = 0; n < 4; ++n)
                V[off + n * 16] = acc[m][n][r] + X[off + n * 16];
        }
    }
}

// ----------------------------- LayerNorm (in-place) ------------------------
__global__ __launch_bounds__(256)
void ln_kernel(float* __restrict__ V, const float* __restrict__ gamma,
               const float* __restrict__ beta) {
    __shared__ float red[8];
    int row = blockIdx.x;
    int tid = threadIdx.x;
    float4 v = *(const float4*)&V[(size_t)row * 1024 + tid * 4];
    float s = v.x + v.y + v.z + v.w;
    float s2 = v.x * v.x + v.y * v.y + v.z * v.z + v.w * v.w;
    #pragma unroll
    for (int off = 32; off; off >>= 1) {
        s  += __shfl_xor(s, off, 64);
        s2 += __shfl_xor(s2, off, 64);
    }
    if ((tid & 63) == 0) { red[(tid >> 6) * 2] = s; red[(tid >> 6) * 2 + 1] = s2; }
    __syncthreads();
    s  = red[0] + red[2] + red[4] + red[6];
    s2 = red[1] + red[3] + red[5] + red[7];
    float mu = s * (1.f / 1024.f);
    float var = s2 * (1.f / 1024.f) - mu * mu;
    float rs = rsqrtf(var + 1e-6f);
    float4 g  = *(const float4*)&gamma[tid * 4];
    float4 be = *(const float4*)&beta[tid * 4];
    float4 o = make_float4((v.x - mu) * rs * g.x + be.x,
                           (v.y - mu) * rs * g.y + be.y,
                           (v.z - mu) * rs * g.z + be.z,
                           (v.w - mu) * rs * g.w + be.w);
    *(float4*)&V[(size_t)row * 1024 + tid * 4] = o;
}

extern "C" void kernel_launch(void* const* d_in, const int* in_sizes, int n_in,
                              void* d_out, int out_size, void* d_ws, size_t ws_size,
                              hipStream_t stream) {
    const float* x     = (const float*)d_in[0];
    const float* W_pe  = (const float*)d_in[1];
    const float* b_pe  = (const float*)d_in[2];
    const float* stt   = (const float*)d_in[3];
    const float* W_fc  = (const float*)d_in[4];
    const float* gamma = (const float*)d_in[5];
    const float* beta  = (const float*)d_in[6];
    float* out = (float*)d_out;

    char* ws = (char*)d_ws;
    unsigned short* avgb  = (unsigned short*)ws;                               // 32 MB
    unsigned short* convb = (unsigned short*)(ws + (size_t)32 * 1024 * 1024);  // 32 MB
    unsigned short* wfcb  = (unsigned short*)(ws + (size_t)64 * 1024 * 1024);  //  2 MB
    float*          segs  = (float*)(ws + (size_t)66 * 1024 * 1024);           //  1 MB

    seg_sum_kernel<<<1024, 256, 0, stream>>>(x, segs);
    avg_kernel<<<1024, 256, 0, stream>>>(x, segs, avgb);
    cvt_kernel<<<1024, 256, 0, stream>>>(W_fc, wfcb);
    conv_kernel<<<4096, 256, 0, stream>>>(avgb, W_pe, b_pe, stt, convb);
    gemm_mfma_kernel<<<1024, 256, 0, stream>>>(convb, wfcb, x, out);
    ln_kernel<<<16384, 256, 0, stream>>>(out, gamma, beta);
}